// Round 9
// baseline (124.511 us; speedup 1.0000x reference)
//
#include <hip/hip_runtime.h>
#include <math.h>

// ---------------- problem constants ----------------
#define SLEN   1024
#define NGRP   4
#define NHEAD  16
#define HPGRP  4
#define DKV    64
#define SCMP   63     // (1024-32)/16+1
#define NBLK   16
#define NSELK  8
#define WWIN   512
#define SCALEF 0.125f // 1/sqrt(64)
#define QBLK   16
#define EXPOFF 8.0f   // fixed softmax offset: exp(sc-8); scores bounded << 80
#define CSTR   2560   // fused QKV GEMM output row stride

typedef __attribute__((ext_vector_type(4))) float f32x4;
typedef __attribute__((ext_vector_type(8))) short bf16x8;

// ---------------- f32 -> bf16 (RNE) helpers ----------------
__device__ __forceinline__ unsigned short f2bf(float f) {
  unsigned u = __float_as_uint(f);
  u += 0x7FFFu + ((u >> 16) & 1u);
  return (unsigned short)(u >> 16);
}
__device__ __forceinline__ unsigned pack2(float a, float b) {
  return (unsigned)f2bf(a) | ((unsigned)f2bf(b) << 16);
}
__device__ __forceinline__ bf16x8 pack8(float4 a, float4 b) {
  union { bf16x8 v; unsigned u[4]; } u;
  u.u[0] = pack2(a.x, a.y); u.u[1] = pack2(a.z, a.w);
  u.u[2] = pack2(b.x, b.y); u.u[3] = pack2(b.z, b.w);
  return u.v;
}

struct ConvJobs {
  const float* src[9];
  unsigned* dst[9];
  int n4[9];
  int cnt;
};

__global__ __launch_bounds__(256) void conv_f32_bf16(ConvJobs jb) {
  const int stride = gridDim.x * blockDim.x;
  for (int t = 0; t < jb.cnt; ++t) {
    const float4* s = (const float4*)jb.src[t];
    uint2* d = (uint2*)jb.dst[t];
    const int n4 = jb.n4[t];
    for (int i = blockIdx.x * blockDim.x + threadIdx.x; i < n4; i += stride) {
      const float4 v = s[i];
      uint2 o;
      o.x = pack2(v.x, v.y);
      o.y = pack2(v.z, v.w);
      d[i] = o;
    }
  }
}

// ---------------- async global->LDS 16B ----------------
__device__ __forceinline__ void gload_lds16(const unsigned short* g, unsigned short* l) {
  __builtin_amdgcn_global_load_lds(
      (const __attribute__((address_space(1))) void*)g,
      (__attribute__((address_space(3))) void*)l, 16, 0, 0);
}

// ---------------- bf16 MFMA GEMM: C[M][N] = A[M][K] @ W[N][K]^T ----------------
// 64x64 tile, 4 waves (2x2), 2x2 fragments each, BK=32.
// 3-buffer LDS pipeline, 2 tiles in flight, counted vmcnt(2), 1 barrier/K-step.
__device__ __forceinline__ void gemm_mfma_body(
    const unsigned short* __restrict__ A, const unsigned short* __restrict__ W,
    float* __restrict__ C, int N, int K, int bm, int bn, int tid)
{
  __shared__ unsigned short As[3][2048];
  __shared__ unsigned short Bs[3][2048];
  const int lane = tid & 63;
  const int wave = tid >> 6;
  const int wr = wave >> 1, wc = wave & 1;

  const int sub = tid >> 6;
  const int kh  = (tid >> 4) & 3;
  const int row = tid & 15;
  const unsigned short* aSrc = A + (size_t)(bm + sub * 16 + row) * K + kh * 8;
  const unsigned short* bSrc = W + (size_t)(bn + sub * 16 + row) * K + kh * 8;
  const int slot = tid * 8;

  f32x4 acc[2][2];
#pragma unroll
  for (int m = 0; m < 2; ++m)
#pragma unroll
    for (int n = 0; n < 2; ++n) acc[m][n] = (f32x4){0.f, 0.f, 0.f, 0.f};

  const int NIT = K >> 5;
  gload_lds16(aSrc + 0,  &As[0][slot]);
  gload_lds16(bSrc + 0,  &Bs[0][slot]);
  gload_lds16(aSrc + 32, &As[1][slot]);
  gload_lds16(bSrc + 32, &Bs[1][slot]);

  for (int i = 0; i < NIT; ++i) {
    __builtin_amdgcn_sched_barrier(0);
    if (i + 1 < NIT) asm volatile("s_waitcnt vmcnt(2)" ::: "memory");
    else             asm volatile("s_waitcnt vmcnt(0)" ::: "memory");
    __builtin_amdgcn_s_barrier();
    __builtin_amdgcn_sched_barrier(0);
    if (i + 2 < NIT) {
      const int nb = (i + 2) % 3;
      gload_lds16(aSrc + (i + 2) * 32, &As[nb][slot]);
      gload_lds16(bSrc + (i + 2) * 32, &Bs[nb][slot]);
    }
    const int cur = i % 3;
    const bf16x8 a0 = *(const bf16x8*)(&As[cur][(wr * 2 + 0) * 512 + lane * 8]);
    const bf16x8 a1 = *(const bf16x8*)(&As[cur][(wr * 2 + 1) * 512 + lane * 8]);
    const bf16x8 b0 = *(const bf16x8*)(&Bs[cur][(wc * 2 + 0) * 512 + lane * 8]);
    const bf16x8 b1 = *(const bf16x8*)(&Bs[cur][(wc * 2 + 1) * 512 + lane * 8]);
    acc[0][0] = __builtin_amdgcn_mfma_f32_16x16x32_bf16(a0, b0, acc[0][0], 0, 0, 0);
    acc[0][1] = __builtin_amdgcn_mfma_f32_16x16x32_bf16(a0, b1, acc[0][1], 0, 0, 0);
    acc[1][0] = __builtin_amdgcn_mfma_f32_16x16x32_bf16(a1, b0, acc[1][0], 0, 0, 0);
    acc[1][1] = __builtin_amdgcn_mfma_f32_16x16x32_bf16(a1, b1, acc[1][1], 0, 0, 0);
  }

  const int cr = (lane >> 4) * 4;
  const int cc = lane & 15;
#pragma unroll
  for (int m = 0; m < 2; ++m)
#pragma unroll
    for (int n = 0; n < 2; ++n) {
      float* cp = C + (size_t)(bm + wr * 32 + m * 16 + cr) * N + (bn + wc * 32 + n * 16 + cc);
#pragma unroll
      for (int r = 0; r < 4; ++r) cp[(size_t)r * N] = acc[m][n][r];
    }
}

__global__ __launch_bounds__(256) void gemm_bf16(
    const unsigned short* __restrict__ A, const unsigned short* __restrict__ W,
    float* __restrict__ C, int N, int K)
{
  gemm_mfma_body(A, W, C, N, K, blockIdx.y * 64, blockIdx.x * 64, threadIdx.x);
}

// ---------------- fused out-proj GEMM: C = (A0+A1) @ W^T, A0/A1 f32 ----------------
// 64x64 tile, 2-buffer, T14 split staging: issue A-loads early, ds_write late.
// All waits compiler-managed (no manual vmcnt — A reg-loads would miscount).
__global__ __launch_bounds__(256) void gemm_out_fused(
    const float* __restrict__ A0, const float* __restrict__ A1,
    const unsigned short* __restrict__ W, float* __restrict__ C)
{
  const int N = 1024, K = 1024;
  const int bm = blockIdx.y * 64, bn = blockIdx.x * 64;
  const int tid = threadIdx.x;
  __shared__ unsigned short As[2][2048];
  __shared__ unsigned short Bs[2][2048];
  const int lane = tid & 63;
  const int wave = tid >> 6;
  const int wr = wave >> 1, wc = wave & 1;

  const int sub = tid >> 6;
  const int kh  = (tid >> 4) & 3;
  const int row = tid & 15;
  const size_t aOff = (size_t)(bm + sub * 16 + row) * K + kh * 8;
  const unsigned short* bSrc = W + (size_t)(bn + sub * 16 + row) * K + kh * 8;
  const int slot = tid * 8;

  f32x4 acc[2][2];
#pragma unroll
  for (int m = 0; m < 2; ++m)
#pragma unroll
    for (int n = 0; n < 2; ++n) acc[m][n] = (f32x4){0.f, 0.f, 0.f, 0.f};

  const int NIT = K >> 5;
  float4 a0lo, a0hi, a1lo, a1hi;

#define ALOAD(k0) do { \
    const float4* p0 = (const float4*)(A0 + aOff + (k0)); \
    const float4* p1 = (const float4*)(A1 + aOff + (k0)); \
    a0lo = p0[0]; a0hi = p0[1]; a1lo = p1[0]; a1hi = p1[1]; \
  } while (0)
#define AWRITE(buf) do { \
    float4 lo, hi; \
    lo.x = a0lo.x + a1lo.x; lo.y = a0lo.y + a1lo.y; \
    lo.z = a0lo.z + a1lo.z; lo.w = a0lo.w + a1lo.w; \
    hi.x = a0hi.x + a1hi.x; hi.y = a0hi.y + a1hi.y; \
    hi.z = a0hi.z + a1hi.z; hi.w = a0hi.w + a1hi.w; \
    *(bf16x8*)(&As[buf][slot]) = pack8(lo, hi); \
  } while (0)

  // prologue: tile 0 fully staged
  ALOAD(0);
  gload_lds16(bSrc + 0, &Bs[0][slot]);
  AWRITE(0);
  __syncthreads();

  for (int i = 0; i < NIT; ++i) {
    const int cur = i & 1, nxt = cur ^ 1;
    if (i + 1 < NIT) {
      ALOAD((i + 1) * 32);                  // issue early (hides under MFMA)
      gload_lds16(bSrc + (i + 1) * 32, &Bs[nxt][slot]);
    }
    const bf16x8 a0 = *(const bf16x8*)(&As[cur][(wr * 2 + 0) * 512 + lane * 8]);
    const bf16x8 a1 = *(const bf16x8*)(&As[cur][(wr * 2 + 1) * 512 + lane * 8]);
    const bf16x8 b0 = *(const bf16x8*)(&Bs[cur][(wc * 2 + 0) * 512 + lane * 8]);
    const bf16x8 b1 = *(const bf16x8*)(&Bs[cur][(wc * 2 + 1) * 512 + lane * 8]);
    acc[0][0] = __builtin_amdgcn_mfma_f32_16x16x32_bf16(a0, b0, acc[0][0], 0, 0, 0);
    acc[0][1] = __builtin_amdgcn_mfma_f32_16x16x32_bf16(a0, b1, acc[0][1], 0, 0, 0);
    acc[1][0] = __builtin_amdgcn_mfma_f32_16x16x32_bf16(a1, b0, acc[1][0], 0, 0, 0);
    acc[1][1] = __builtin_amdgcn_mfma_f32_16x16x32_bf16(a1, b1, acc[1][1], 0, 0, 0);
    if (i + 1 < NIT) AWRITE(nxt);           // write late (after compute)
    __syncthreads();
  }
#undef ALOAD
#undef AWRITE

  const int cr = (lane >> 4) * 4;
  const int cc = lane & 15;
#pragma unroll
  for (int m = 0; m < 2; ++m)
#pragma unroll
    for (int n = 0; n < 2; ++n) {
      float* cp = C + (size_t)(bm + wr * 32 + m * 16 + cr) * N + (bn + wc * 32 + n * 16 + cc);
#pragma unroll
      for (int r = 0; r < 4; ++r) cp[(size_t)r * N] = acc[m][n][r];
    }
}

// ---------------- merged mid kernel: prep(1024) | transpose(512) | pool(64) ----------------
// C = [1024][2560] f32: q 0-1023 | ksel 1024 | vsel 1280 | kwin 1536 | vwin 1792 | kcmp 2048 | vcmp 2304
__global__ __launch_bounds__(256) void mid_kernel(
    const float* __restrict__ C,
    const float* __restrict__ g1w, const float* __restrict__ g1b,
    const float* __restrict__ g2w, const float* __restrict__ g2b,
    unsigned short* __restrict__ q_b,
    unsigned short* __restrict__ kselb, unsigned short* __restrict__ kwinb,
    float* __restrict__ gates,
    unsigned short* __restrict__ vselT, unsigned short* __restrict__ vwinT,
    unsigned short* __restrict__ KcB, unsigned short* __restrict__ VcTB)
{
  const int b = blockIdx.x;
  const int t = threadIdx.x;

  __shared__ float csS[32], snS[32];
  __shared__ float qs[1024];
  __shared__ float qgS[4][64];
  __shared__ float h1S[4][32];
  __shared__ float glS[4][3];
  __shared__ float tile[32][33];
  __shared__ float csP[32][32], snP[32][32];

  if (b < 1024) {
    const int s = b;
    if (t < 32) {
      const float inv = powf(10000.f, -(float)t * (1.f / 32.f));
      float sn, cs;
      sincosf((float)s * inv, &sn, &cs);
      csS[t] = cs; snS[t] = sn;
    }
    __syncthreads();
    {
      const int ht = t >> 4;
      const float* qr = C + (size_t)s * CSTR + ht * 64;
#pragma unroll
      for (int i = 0; i < 2; ++i) {
        const int dd = (t & 15) * 2 + i;
        const float x1 = qr[dd], x2 = qr[dd + 32];
        qs[ht * 64 + dd]      = x1 * csS[dd] - x2 * snS[dd];
        qs[ht * 64 + dd + 32] = x1 * snS[dd] + x2 * csS[dd];
      }
    }
    {
      const int which = t >> 7;
      const int g = (t >> 5) & 3, dd = t & 31;
      const float* src = C + (size_t)s * CSTR + (which ? 1536 : 1024) + g * 64;
      unsigned short* dst = (which ? kwinb : kselb) + (size_t)s * 256 + g * 64;
      const float x1 = src[dd], x2 = src[dd + 32];
      dst[dd]      = f2bf(x1 * csS[dd] - x2 * snS[dd]);
      dst[dd + 32] = f2bf(x1 * snS[dd] + x2 * csS[dd]);
    }
    __syncthreads();
    {
      uint2 o;
      o.x = pack2(qs[t * 4 + 0], qs[t * 4 + 1]);
      o.y = pack2(qs[t * 4 + 2], qs[t * 4 + 3]);
      *(uint2*)(q_b + (size_t)s * 1024 + t * 4) = o;
    }
    {
      const int g = t >> 6, d = t & 63;
      qgS[g][d] = (qs[g * 256 + d] + qs[g * 256 + 64 + d] +
                   qs[g * 256 + 128 + d] + qs[g * 256 + 192 + d]) * 0.25f;
    }
    __syncthreads();
    if (t < 128) {
      const int g = t >> 5, j = t & 31;
      float a = g1b[j];
      for (int d = 0; d < 64; ++d) a += qgS[g][d] * g1w[j * 64 + d];
      h1S[g][j] = a / (1.f + expf(-a));
    }
    __syncthreads();
    if (t < 16) {
      const int g = t >> 2, rr = t & 3;
      if (rr < 3) {
        float a = g2b[rr];
        for (int j = 0; j < 32; ++j) a += h1S[g][j] * g2w[rr * 32 + j];
        glS[g][rr] = a;
      }
    }
    __syncthreads();
    if (t < 4) {
      const int g = t;
      const float gl0 = glS[g][0], gl1 = glS[g][1], gl2 = glS[g][2];
      const float m1 = fmaxf(gl0, fmaxf(gl1, gl2));
      const float e0 = expf(gl0 - m1), e1 = expf(gl1 - m1), e2 = expf(gl2 - m1);
      const float inv = 1.f / (e0 + e1 + e2);
      float p0 = e0 * inv, p1 = e1 * inv, p2 = e2 * inv;
      int am = 0; float best = gl0;
      if (gl1 > best) { best = gl1; am = 1; }
      if (gl2 > best) { best = gl2; am = 2; }
      float second = -INFINITY;
      if (am != 0) second = fmaxf(second, gl0);
      if (am != 1) second = fmaxf(second, gl1);
      if (am != 2) second = fmaxf(second, gl2);
      if (best - second > 50.f) {
        p0 = (am == 0) ? 1.f : 0.f; p1 = (am == 1) ? 1.f : 0.f; p2 = (am == 2) ? 1.f : 0.f;
      }
      float* o = gates + (size_t)(s * 4 + g) * 3;
      o[0] = p0; o[1] = p1; o[2] = p2;
    }
  } else if (b < 1536) {
    const int idx = b - 1024;
    const int tr = (idx & 31) * 32, tc = ((idx >> 5) & 7) * 32;
    const int z = idx >> 8;
    const int off = z ? 1792 : 1280;
    unsigned short* dst = z ? vwinT : vselT;
    const int r = t >> 5, c = t & 31;
#pragma unroll
    for (int i = 0; i < 4; ++i)
      tile[r + i * 8][c] = C[(size_t)(tr + r + i * 8) * CSTR + off + tc + c];
    __syncthreads();
#pragma unroll
    for (int i = 0; i < 4; ++i)
      dst[(size_t)(tc + r + i * 8) * 1024 + tr + c] = f2bf(tile[c][r + i * 8]);
  } else {
    const int c = b - 1536;          // 0..63 (63 = zero pad)
    const int g = t >> 6, d = t & 63;
#pragma unroll
    for (int qq = 0; qq < 4; ++qq) {
      const int idx = t * 4 + qq;
      const int j = idx >> 5, dd = idx & 31;
      const float inv = powf(10000.f, -(float)dd * (1.f / 32.f));
      float sn, cs;
      sincosf((float)(c * 16 + j) * inv, &sn, &cs);
      csP[j][dd] = cs; snP[j][dd] = sn;
    }
    __syncthreads();
    float ak = 0.f, av = 0.f;
    if (c < SCMP) {
      const int d2 = d & 31;
      for (int j = 0; j < 32; ++j) {
        const int pos = c * 16 + j;
        const float k1 = C[(size_t)pos * CSTR + 2048 + g * 64 + d2];
        const float k2 = C[(size_t)pos * CSTR + 2048 + g * 64 + d2 + 32];
        ak += (d < 32) ? (k1 * csP[j][d2] - k2 * snP[j][d2])
                       : (k1 * snP[j][d2] + k2 * csP[j][d2]);
        av += C[(size_t)pos * CSTR + 2304 + g * 64 + d];
      }
      ak *= (1.f / 32.f); av *= (1.f / 32.f);
    }
    KcB[(size_t)(g * 64 + c) * 64 + d] = f2bf(ak);
    VcTB[(size_t)(g * 64 + d) * 64 + c] = f2bf(av);
  }
}

// ---------------- MFMA NSA attention (round-6 fused structure) ----------------
// grid = (64 qtiles of 16 rows, 4 groups, 2): z=0 -> cmp+sel (Ocs), z=1 -> win (Owin).
// 4 waves = 4 heads. Fixed-offset softmax, deferred denominator.
// Tile loop: 3-buffer LDS, 1-ahead prefetch, counted vmcnt(4), one raw s_barrier/tile.
__device__ __forceinline__ void stage_tile(
    const unsigned short* kbase, int krow,
    const unsigned short* vbase, int vrow,
    unsigned short* Kb, unsigned short* Vb, int tid)
{
#pragma unroll
  for (int i = 0; i < 2; ++i) {
    const int t2 = tid + i * 256;
    const int sf = t2 >> 7, sks = (t2 >> 6) & 1, skh = (t2 >> 4) & 3, stk = t2 & 15;
    gload_lds16(kbase + (size_t)(16 * sf + stk) * krow + sks * 32 + skh * 8, Kb + t2 * 8);
    gload_lds16(vbase + (size_t)(16 * sf + stk) * vrow + sks * 32 + skh * 8, Vb + t2 * 8);
  }
}

// BR: 0=cmp, 1=sel (per-row 16-bit block mask), 2=win (sliding window)
template<int BR>
__device__ __forceinline__ void attn_compute(
    int b, int s0, int l,
    bf16x8 aq0, bf16x8 aq1,
    float (&ps)[4], f32x4 (&Oa)[4],
    const unsigned short* Klds, const unsigned short* Vlds,
    float (*Pw)[68], const unsigned* selmaskS)
{
  const int kg = l >> 4, lr = l & 15;
  f32x4 sc[4];
  __builtin_amdgcn_s_setprio(1);
#pragma unroll
  for (int f = 0; f < 4; ++f) {
    sc[f] = (f32x4){0.f, 0.f, 0.f, 0.f};
    sc[f] = __builtin_amdgcn_mfma_f32_16x16x32_bf16(
        aq0, *(const bf16x8*)(Klds + (f * 2 + 0) * 512 + l * 8), sc[f], 0, 0, 0);
    sc[f] = __builtin_amdgcn_mfma_f32_16x16x32_bf16(
        aq1, *(const bf16x8*)(Klds + (f * 2 + 1) * 512 + l * 8), sc[f], 0, 0, 0);
  }
  __builtin_amdgcn_s_setprio(0);

#pragma unroll
  for (int r = 0; r < 4; ++r) {
    const int lrow = kg * 4 + r;
    const int sr = s0 + lrow;
#pragma unroll
    for (int f = 0; f < 4; ++f) {
      const int tok = b * 64 + 16 * f + lr;
      bool ok;
      if (BR == 0)      ok = (tok < SCMP) && (tok * 16 + 31 <= sr);
      else if (BR == 1) ok = ((selmaskS[lrow] >> b) & 1u) && (tok <= sr);
      else              ok = (tok <= sr) && (tok > sr - WWIN);
      const float p = ok ? __expf(sc[f][r] * SCALEF - EXPOFF) : 0.f;
      Pw[lrow][16 * f + lr] = p;
      ps[r] += p;
    }
  }
  asm volatile("s_waitcnt lgkmcnt(0)" ::: "memory");  // wave's P writes visible
#pragma unroll
  for (int ks = 0; ks < 2; ++ks) {
    const float4 pa0 = *(const float4*)&Pw[lr][ks * 32 + kg * 8];
    const float4 pa1 = *(const float4*)&Pw[lr][ks * 32 + kg * 8 + 4];
    const bf16x8 pa = pack8(pa0, pa1);
    __builtin_amdgcn_s_setprio(1);
#pragma unroll
    for (int f = 0; f < 4; ++f)
      Oa[f] = __builtin_amdgcn_mfma_f32_16x16x32_bf16(
          pa, *(const bf16x8*)(Vlds + (f * 2 + ks) * 512 + l * 8), Oa[f], 0, 0, 0);
    __builtin_amdgcn_s_setprio(0);
  }
}

#define TILE_SYNC(more) do { \
    __builtin_amdgcn_sched_barrier(0); \
    if (more) asm volatile("s_waitcnt vmcnt(4)" ::: "memory"); \
    else      asm volatile("s_waitcnt vmcnt(0)" ::: "memory"); \
    __builtin_amdgcn_sched_barrier(0); \
    __builtin_amdgcn_s_barrier(); \
    __builtin_amdgcn_sched_barrier(0); \
  } while (0)

__global__ __launch_bounds__(256) void attn_mfma_kernel(
    const unsigned short* __restrict__ qb,     // [S][16][64] bf16 (roped)
    const unsigned short* __restrict__ kselb,  // [S][256] bf16 (roped)
    const unsigned short* __restrict__ vselT,  // [256][S] bf16
    const unsigned short* __restrict__ kwinb,
    const unsigned short* __restrict__ vwinT,
    const unsigned short* __restrict__ KcB,    // [g*64+c][64] bf16
    const unsigned short* __restrict__ VcTB,   // [g*64+d][64] bf16
    const float* __restrict__ gates,           // [S][4][3]
    float* __restrict__ Ocs, float* __restrict__ Owin)
{
  const int qt = blockIdx.x;
  const int g  = blockIdx.y;
  const int z  = blockIdx.z;
  const int s0 = qt * QBLK;
  const int tid = threadIdx.x;
  const int w = tid >> 6, l = tid & 63;    // w = head
  const int kg = l >> 4, lr = l & 15;
  const int bmax = s0 >> 6;

  __shared__ unsigned short Klds[3][4096];
  __shared__ unsigned short Vlds[3][4096];
  __shared__ float Plds[4][16][68];
  __shared__ float lgS[QBLK][16];
  __shared__ float lcS[4][16];
  __shared__ unsigned selmaskS[QBLK];
  __shared__ int selListS[16];
  __shared__ int nselS;

  if (tid < QBLK) selmaskS[tid] = 0u;

  const int sq = s0 + lr;
  const unsigned short* qrow = qb + (size_t)(sq * 16 + g * 4 + w) * 64;
  const bf16x8 aq0 = *(const bf16x8*)(qrow + kg * 8);
  const bf16x8 aq1 = *(const bf16x8*)(qrow + 32 + kg * 8);

  float gv[3][4];
#pragma unroll
  for (int r = 0; r < 4; ++r) {
    const int sr = s0 + kg * 4 + r;
    const float* gp = gates + (size_t)(sr * 4 + g) * 3;
    gv[0][r] = gp[0]; gv[1][r] = gp[1]; gv[2][r] = gp[2];
  }

  f32x4 Ot[4];
#pragma unroll
  for (int f = 0; f < 4; ++f) Ot[f] = (f32x4){0.f, 0.f, 0.f, 0.f};

  float ps[4], ls[4];
  f32x4 Oa[4];

#define ARESET() do { \
    _Pragma("unroll") for (int r = 0; r < 4; ++r) ps[r] = 0.f; \
    _Pragma("unroll") for (int f = 0; f < 4; ++f) Oa[f] = (f32x4){0.f,0.f,0.f,0.f}; \
  } while (0)
#define REDUCE_LS() do { \
    _Pragma("unroll") for (int r = 0; r < 4; ++r) { \
      ls[r] = ps[r]; \
      ls[r] += __shfl_xor(ls[r], 1); ls[r] += __shfl_xor(ls[r], 2); \
      ls[r] += __shfl_xor(ls[r], 4); ls[r] += __shfl_xor(ls[r], 8); } \
  } while (0)
#define AFINAL(bi) do { \
    _Pragma("unroll") for (int f = 0; f < 4; ++f) \
    _Pragma("unroll") for (int r = 0; r < 4; ++r) \
      Ot[f][r] += gv[bi][r] * ((ls[r] > 0.f) ? (Oa[f][r] / ls[r]) : 0.f); \
  } while (0)

  if (z == 0) {
    // ---- cmp branch (single tile) ----
    ARESET();
    stage_tile(KcB + (size_t)g * 64 * 64, 64, VcTB + (size_t)g * 64 * 64, 64,
               Klds[0], Vlds[0], tid);
    TILE_SYNC(0);
    attn_compute<0>(0, s0, l, aq0, aq1, ps, Oa, Klds[0], Vlds[0], Plds[w], selmaskS);
    REDUCE_LS();
    if ((l & 15) == 0) {
#pragma unroll
      for (int r = 0; r < 4; ++r) lcS[w][kg * 4 + r] = ls[r];
    }
    AFINAL(0);
    __syncthreads();   // cmp P + lcS visible block-wide

    // ---- selection: p_slc (M_MAP inline), lg, top-8 ----
    {
      const int row = tid >> 4, mm = tid & 15;
      float psl = 0.f;
#pragma unroll
      for (int hh = 0; hh < 4; ++hh) {
        const float lc = lcS[hh][row];
        if (lc > 0.f) {
          const int cb = 4 * mm;
          float a = Plds[hh][row][cb] + Plds[hh][row][cb + 1] + Plds[hh][row][cb + 2];
          if (cb >= 1)       a += 0.5f * Plds[hh][row][cb - 1];
          if (cb + 3 < SCMP) a += 0.5f * Plds[hh][row][cb + 3];
          psl += a / lc;
        }
      }
      const bool causal = (mm <= bmax);
      const bool forced = (mm == 0) || (mm == bmax);
      lgS[row][mm] = causal ? (psl + (forced ? 1e6f : 0.f)) : -1e9f;
    }
    __syncthreads();
    {
      const int row = tid >> 4, mm = tid & 15;
      const float my = lgS[row][mm];
      int rank = 0;
#pragma unroll
      for (int m2 = 0; m2 < 16; ++m2) {
        const float v = lgS[row][m2];
        if (v > my || (v == my && m2 < mm)) ++rank;
      }
      if (rank < NSELK && mm <= bmax) atomicOr(&selmaskS[row], 1u << mm);
    }
    __syncthreads();
    if (tid == 0) {
      unsigned u = 0;
      for (int r = 0; r < QBLK; ++r) u |= selmaskS[r];
      int n = 0;
      for (int b = 0; b < 16; ++b) if ((u >> b) & 1u) selListS[n++] = b;
      nselS = n;
    }
    __syncthreads();
    const int nt = nselS;   // >= 1

    // ---- sel branch: 3-buffer counted-vmcnt pipeline ----
    ARESET();
    {
      const int b0 = selListS[0];
      stage_tile(kselb + (size_t)b0 * 64 * 256 + g * 64, 256,
                 vselT + (size_t)g * 64 * 1024 + b0 * 64, 1024,
                 Klds[0], Vlds[0], tid);
      for (int i = 0; i < nt; ++i) {
        if (i + 1 < nt) {
          const int bn = selListS[i + 1];
          const int nb = (i + 1) % 3;
          stage_tile(kselb + (size_t)bn * 64 * 256 + g * 64, 256,
                     vselT + (size_t)g * 64 * 1024 + bn * 64, 1024,
                     Klds[nb], Vlds[nb], tid);
        }
        TILE_SYNC(i + 1 < nt);
        attn_compute<1>(selListS[i], s0, l, aq0, aq1, ps, Oa,
                        Klds[i % 3], Vlds[i % 3], Plds[w], selmaskS);
        __builtin_amdgcn_sched_barrier(0);
      }
    }
    REDUCE_LS();
    AFINAL(1);

#pragma unroll
    for (int f = 0; f < 4; ++f)
#pragma unroll
      for (int r = 0; r < 4; ++r) {
        const int sr = s0 + kg * 4 + r;
        Ocs[(size_t)(sr * 16 + g * 4 + w) * 64 + 16 * f + lr] = Ot[f][r];
      }
  } else {
    // ---- win branch: 3-buffer counted-vmcnt pipeline ----
    ARESET();
    const int blo = (s0 >= (WWIN - 1)) ? ((s0 - (WWIN - 1)) >> 6) : 0;
    const int nt = bmax - blo + 1;
    stage_tile(kwinb + (size_t)blo * 64 * 256 + g * 64, 256,
               vwinT + (size_t)g * 64 * 1024 + blo * 64, 1024,
               Klds[0], Vlds[0], tid);
    for (int i = 0; i < nt; ++i) {
      if (i + 1 < nt) {
        const int bn = blo + i + 1;
        const int nb = (i + 1) % 3;
        stage_tile(kwinb + (size_t)bn * 64 * 256 + g * 64, 256,
                   vwinT + (size_t)g * 64 * 1024 + bn * 64, 1024,
                   Klds[nb], Vlds[nb], tid);
      }
      TILE_SYNC(i + 1 < nt);
      attn_compute<2>(blo + i, s0, l, aq0, aq1, ps, Oa,
                      Klds[i % 3], Vlds[i % 3], Plds[w], selmaskS);
      __builtin_amdgcn_sched_barrier(0);
    }
    REDUCE_LS();
    AFINAL(2);

#pragma unroll
    for (int f = 0; f < 4; ++f)
#pragma unroll
      for (int r = 0; r < 4; ++r) {
        const int sr = s0 + kg * 4 + r;
        Owin[(size_t)(sr * 16 + g * 4 + w) * 64 + 16 * f + lr] = Ot[f][r];
      }
  }
#undef ARESET
#undef REDUCE_LS
#undef AFINAL
}

// ---------------- launch ----------------
extern "C" void kernel_launch(void* const* d_in, const int* in_sizes, int n_in,
                              void* d_out, int out_size, void* d_ws, size_t ws_size,
                              hipStream_t stream) {
  const float* x      = (const float*)d_in[0];
  const float* wq     = (const float*)d_in[1];
  const float* wk_sel = (const float*)d_in[2];
  const float* wv_sel = (const float*)d_in[3];
  const float* wk_win = (const float*)d_in[4];
  const float* wv_win = (const float*)d_in[5];
  const float* wk_cmp = (const float*)d_in[6];
  const float* wv_cmp = (const float*)d_in[7];
  const float* w_out  = (const float*)d_in[8];
  const float* g1w    = (const float*)d_in[9];
  const float* g1b    = (const float*)d_in[10];
  const float* g2w    = (const float*)d_in[11];
  const float* g2b    = (const float*)d_in[12];

  float* ws = (float*)d_ws;
  float* Cq    = ws;                          // 2,621,440
  float* gts   = Cq + 2621440;                // 12,288
  float* Ocs   = gts + 12288;                 // 1,048,576
  float* Owin  = Ocs + 1048576;               // 1,048,576

  unsigned short* xb     = (unsigned short*)(Owin + 1048576);  // 1,048,576
  unsigned short* wqkvb  = xb + 1048576;      // 2,621,440 (wq | 6 kv weights)
  unsigned short* w_outb = wqkvb + 2621440;   // 1,048,576
  unsigned short* q_b    = w_outb + 1048576;  // 1,048,576
  unsigned short* kselb  = q_b + 1048576;     // 262,144
  unsigned short* kwinb  = kselb + 262144;    // 262,144
  unsigned short* vselT  = kwinb + 262144;    // 262,144
  unsigned short* vwinT  = vselT + 262144;    // 262,144
  unsigned short* KcB    = vwinT + 262144;    // 16,384
  unsigned short* VcTB   = KcB + 16384;       // 16,384

  // inputs -> bf16 (weights contiguous: wq rows 0-1023, then 6 kv weights)
  ConvJobs j1 = {};
  j1.cnt = 9;
  j1.src[0] = x;      j1.dst[0] = (unsigned*)xb;                        j1.n4[0] = 262144;
  j1.src[1] = wq;     j1.dst[1] = (unsigned*)wqkvb;                     j1.n4[1] = 262144;
  j1.src[2] = wk_sel; j1.dst[2] = (unsigned*)(wqkvb + 1048576);         j1.n4[2] = 65536;
  j1.src[3] = wv_sel; j1.dst[3] = (unsigned*)(wqkvb + 1048576+262144);  j1.n4[3] = 65536;
  j1.src[4] = wk_win; j1.dst[4] = (unsigned*)(wqkvb + 1048576+524288);  j1.n4[4] = 65536;
  j1.src[5] = wv_win; j1.dst[5] = (unsigned*)(wqkvb + 1048576+786432);  j1.n4[5] = 65536;
  j1.src[6] = wk_cmp; j1.dst[6] = (unsigned*)(wqkvb + 1048576+1048576); j1.n4[6] = 65536;
  j1.src[7] = wv_cmp; j1.dst[7] = (unsigned*)(wqkvb + 1048576+1310720); j1.n4[7] = 65536;
  j1.src[8] = w_out;  j1.dst[8] = (unsigned*)w_outb;                    j1.n4[8] = 262144;
  conv_f32_bf16<<<1024, 256, 0, stream>>>(j1);

  // fused QKV projection: Cq[1024][2560] = x @ [wq; kv weights]^T  (64x64 tiles, 640 blocks)
  gemm_bf16<<<dim3(40, 16), 256, 0, stream>>>(xb, wqkvb, Cq, CSTR, 1024);

  // merged prep | transpose | pool
  mid_kernel<<<1600, 256, 0, stream>>>(Cq, g1w, g1b, g2w, g2b,
                                       q_b, kselb, kwinb, gts,
                                       vselT, vwinT, KcB, VcTB);

  // fused MFMA NSA attention (z=0: cmp+sel, z=1: win)
  attn_mfma_kernel<<<dim3(64, 4, 2), 256, 0, stream>>>(
      q_b, kselb, vselT, kwinb, vwinT, KcB, VcTB, gts, Ocs, Owin);

  // output projection with fused (Ocs + Owin) -> bf16 A-staging
  gemm_out_fused<<<dim3(16, 16), 256, 0, stream>>>(Ocs, Owin, w_outb, (float*)d_out);
}

// Round 10
// 112.499 us; speedup vs baseline: 1.1068x; 1.1068x over previous
//
#include <hip/hip_runtime.h>
#include <math.h>

// ---------------- problem constants ----------------
#define SLEN   1024
#define NGRP   4
#define NHEAD  16
#define HPGRP  4
#define DKV    64
#define SCMP   63     // (1024-32)/16+1
#define NBLK   16
#define NSELK  8
#define WWIN   512
#define SCALEF 0.125f // 1/sqrt(64)
#define QBLK   16
#define EXPOFF 8.0f   // fixed softmax offset: exp(sc-8); scores bounded << 80
#define CSTR   2560   // fused QKV GEMM output row stride

typedef __attribute__((ext_vector_type(4))) float f32x4;
typedef __attribute__((ext_vector_type(8))) short bf16x8;

// ---------------- f32 -> bf16 (RNE) helpers ----------------
__device__ __forceinline__ unsigned short f2bf(float f) {
  unsigned u = __float_as_uint(f);
  u += 0x7FFFu + ((u >> 16) & 1u);
  return (unsigned short)(u >> 16);
}
__device__ __forceinline__ unsigned pack2(float a, float b) {
  return (unsigned)f2bf(a) | ((unsigned)f2bf(b) << 16);
}
__device__ __forceinline__ bf16x8 pack8(float4 a, float4 b) {
  union { bf16x8 v; unsigned u[4]; } u;
  u.u[0] = pack2(a.x, a.y); u.u[1] = pack2(a.z, a.w);
  u.u[2] = pack2(b.x, b.y); u.u[3] = pack2(b.z, b.w);
  return u.v;
}

struct ConvJobs {
  const float* src[9];
  unsigned* dst[9];
  int n4[9];
  int cnt;
};

__global__ __launch_bounds__(256) void conv_f32_bf16(ConvJobs jb) {
  const int stride = gridDim.x * blockDim.x;
  for (int t = 0; t < jb.cnt; ++t) {
    const float4* s = (const float4*)jb.src[t];
    uint2* d = (uint2*)jb.dst[t];
    const int n4 = jb.n4[t];
    for (int i = blockIdx.x * blockDim.x + threadIdx.x; i < n4; i += stride) {
      const float4 v = s[i];
      uint2 o;
      o.x = pack2(v.x, v.y);
      o.y = pack2(v.z, v.w);
      d[i] = o;
    }
  }
}

// sum two f32 buffers -> bf16
__global__ __launch_bounds__(256) void conv_add_bf16(
    const float* __restrict__ a, const float* __restrict__ b, uint2* __restrict__ d)
{
  const int i = blockIdx.x * 256 + threadIdx.x;
  const float4 va = ((const float4*)a)[i];
  const float4 vb = ((const float4*)b)[i];
  uint2 o;
  o.x = pack2(va.x + vb.x, va.y + vb.y);
  o.y = pack2(va.z + vb.z, va.w + vb.w);
  d[i] = o;
}

// ---------------- async global->LDS 16B ----------------
__device__ __forceinline__ void gload_lds16(const unsigned short* g, unsigned short* l) {
  __builtin_amdgcn_global_load_lds(
      (const __attribute__((address_space(1))) void*)g,
      (__attribute__((address_space(3))) void*)l, 16, 0, 0);
}

// ---------------- bf16 MFMA GEMM: C[M][N] = A[M][K] @ W[N][K]^T ----------------
// 64x64 tile, 4 waves (2x2), 2x2 fragments each, BK=32.
// 3-buffer LDS pipeline, 2 tiles in flight, counted vmcnt(2), 1 barrier/K-step.
__device__ __forceinline__ void gemm_mfma_body(
    const unsigned short* __restrict__ A, const unsigned short* __restrict__ W,
    float* __restrict__ C, int N, int K, int bm, int bn, int tid)
{
  __shared__ unsigned short As[3][2048];
  __shared__ unsigned short Bs[3][2048];
  const int lane = tid & 63;
  const int wave = tid >> 6;
  const int wr = wave >> 1, wc = wave & 1;

  const int sub = tid >> 6;
  const int kh  = (tid >> 4) & 3;
  const int row = tid & 15;
  const unsigned short* aSrc = A + (size_t)(bm + sub * 16 + row) * K + kh * 8;
  const unsigned short* bSrc = W + (size_t)(bn + sub * 16 + row) * K + kh * 8;
  const int slot = tid * 8;

  f32x4 acc[2][2];
#pragma unroll
  for (int m = 0; m < 2; ++m)
#pragma unroll
    for (int n = 0; n < 2; ++n) acc[m][n] = (f32x4){0.f, 0.f, 0.f, 0.f};

  const int NIT = K >> 5;
  gload_lds16(aSrc + 0,  &As[0][slot]);
  gload_lds16(bSrc + 0,  &Bs[0][slot]);
  gload_lds16(aSrc + 32, &As[1][slot]);
  gload_lds16(bSrc + 32, &Bs[1][slot]);

  for (int i = 0; i < NIT; ++i) {
    __builtin_amdgcn_sched_barrier(0);
    if (i + 1 < NIT) asm volatile("s_waitcnt vmcnt(2)" ::: "memory");
    else             asm volatile("s_waitcnt vmcnt(0)" ::: "memory");
    __builtin_amdgcn_s_barrier();
    __builtin_amdgcn_sched_barrier(0);
    if (i + 2 < NIT) {
      const int nb = (i + 2) % 3;
      gload_lds16(aSrc + (i + 2) * 32, &As[nb][slot]);
      gload_lds16(bSrc + (i + 2) * 32, &Bs[nb][slot]);
    }
    const int cur = i % 3;
    const bf16x8 a0 = *(const bf16x8*)(&As[cur][(wr * 2 + 0) * 512 + lane * 8]);
    const bf16x8 a1 = *(const bf16x8*)(&As[cur][(wr * 2 + 1) * 512 + lane * 8]);
    const bf16x8 b0 = *(const bf16x8*)(&Bs[cur][(wc * 2 + 0) * 512 + lane * 8]);
    const bf16x8 b1 = *(const bf16x8*)(&Bs[cur][(wc * 2 + 1) * 512 + lane * 8]);
    acc[0][0] = __builtin_amdgcn_mfma_f32_16x16x32_bf16(a0, b0, acc[0][0], 0, 0, 0);
    acc[0][1] = __builtin_amdgcn_mfma_f32_16x16x32_bf16(a0, b1, acc[0][1], 0, 0, 0);
    acc[1][0] = __builtin_amdgcn_mfma_f32_16x16x32_bf16(a1, b0, acc[1][0], 0, 0, 0);
    acc[1][1] = __builtin_amdgcn_mfma_f32_16x16x32_bf16(a1, b1, acc[1][1], 0, 0, 0);
  }

  const int cr = (lane >> 4) * 4;
  const int cc = lane & 15;
#pragma unroll
  for (int m = 0; m < 2; ++m)
#pragma unroll
    for (int n = 0; n < 2; ++n) {
      float* cp = C + (size_t)(bm + wr * 32 + m * 16 + cr) * N + (bn + wc * 32 + n * 16 + cc);
#pragma unroll
      for (int r = 0; r < 4; ++r) cp[(size_t)r * N] = acc[m][n][r];
    }
}

__global__ __launch_bounds__(256) void gemm_bf16(
    const unsigned short* __restrict__ A, const unsigned short* __restrict__ W,
    float* __restrict__ C, int N, int K)
{
  gemm_mfma_body(A, W, C, N, K, blockIdx.y * 64, blockIdx.x * 64, threadIdx.x);
}

// ---------------- merged mid kernel: prep(1024) | transpose(512) | pool(64) ----------------
// C = [1024][2560] f32: q 0-1023 | ksel 1024 | vsel 1280 | kwin 1536 | vwin 1792 | kcmp 2048 | vcmp 2304
__global__ __launch_bounds__(256) void mid_kernel(
    const float* __restrict__ C,
    const float* __restrict__ g1w, const float* __restrict__ g1b,
    const float* __restrict__ g2w, const float* __restrict__ g2b,
    unsigned short* __restrict__ q_b,
    unsigned short* __restrict__ kselb, unsigned short* __restrict__ kwinb,
    float* __restrict__ gates,
    unsigned short* __restrict__ vselT, unsigned short* __restrict__ vwinT,
    unsigned short* __restrict__ KcB, unsigned short* __restrict__ VcTB)
{
  const int b = blockIdx.x;
  const int t = threadIdx.x;

  __shared__ float csS[32], snS[32];
  __shared__ float qs[1024];
  __shared__ float qgS[4][64];
  __shared__ float h1S[4][32];
  __shared__ float glS[4][3];
  __shared__ float tile[32][33];
  __shared__ float csP[32][32], snP[32][32];

  if (b < 1024) {
    const int s = b;
    if (t < 32) {
      const float inv = powf(10000.f, -(float)t * (1.f / 32.f));
      float sn, cs;
      sincosf((float)s * inv, &sn, &cs);
      csS[t] = cs; snS[t] = sn;
    }
    __syncthreads();
    {
      const int ht = t >> 4;
      const float* qr = C + (size_t)s * CSTR + ht * 64;
#pragma unroll
      for (int i = 0; i < 2; ++i) {
        const int dd = (t & 15) * 2 + i;
        const float x1 = qr[dd], x2 = qr[dd + 32];
        qs[ht * 64 + dd]      = x1 * csS[dd] - x2 * snS[dd];
        qs[ht * 64 + dd + 32] = x1 * snS[dd] + x2 * csS[dd];
      }
    }
    {
      const int which = t >> 7;
      const int g = (t >> 5) & 3, dd = t & 31;
      const float* src = C + (size_t)s * CSTR + (which ? 1536 : 1024) + g * 64;
      unsigned short* dst = (which ? kwinb : kselb) + (size_t)s * 256 + g * 64;
      const float x1 = src[dd], x2 = src[dd + 32];
      dst[dd]      = f2bf(x1 * csS[dd] - x2 * snS[dd]);
      dst[dd + 32] = f2bf(x1 * snS[dd] + x2 * csS[dd]);
    }
    __syncthreads();
    {
      uint2 o;
      o.x = pack2(qs[t * 4 + 0], qs[t * 4 + 1]);
      o.y = pack2(qs[t * 4 + 2], qs[t * 4 + 3]);
      *(uint2*)(q_b + (size_t)s * 1024 + t * 4) = o;
    }
    {
      const int g = t >> 6, d = t & 63;
      qgS[g][d] = (qs[g * 256 + d] + qs[g * 256 + 64 + d] +
                   qs[g * 256 + 128 + d] + qs[g * 256 + 192 + d]) * 0.25f;
    }
    __syncthreads();
    if (t < 128) {
      const int g = t >> 5, j = t & 31;
      float a = g1b[j];
      for (int d = 0; d < 64; ++d) a += qgS[g][d] * g1w[j * 64 + d];
      h1S[g][j] = a / (1.f + expf(-a));
    }
    __syncthreads();
    if (t < 16) {
      const int g = t >> 2, rr = t & 3;
      if (rr < 3) {
        float a = g2b[rr];
        for (int j = 0; j < 32; ++j) a += h1S[g][j] * g2w[rr * 32 + j];
        glS[g][rr] = a;
      }
    }
    __syncthreads();
    if (t < 4) {
      const int g = t;
      const float gl0 = glS[g][0], gl1 = glS[g][1], gl2 = glS[g][2];
      const float m1 = fmaxf(gl0, fmaxf(gl1, gl2));
      const float e0 = expf(gl0 - m1), e1 = expf(gl1 - m1), e2 = expf(gl2 - m1);
      const float inv = 1.f / (e0 + e1 + e2);
      float p0 = e0 * inv, p1 = e1 * inv, p2 = e2 * inv;
      int am = 0; float best = gl0;
      if (gl1 > best) { best = gl1; am = 1; }
      if (gl2 > best) { best = gl2; am = 2; }
      float second = -INFINITY;
      if (am != 0) second = fmaxf(second, gl0);
      if (am != 1) second = fmaxf(second, gl1);
      if (am != 2) second = fmaxf(second, gl2);
      if (best - second > 50.f) {
        p0 = (am == 0) ? 1.f : 0.f; p1 = (am == 1) ? 1.f : 0.f; p2 = (am == 2) ? 1.f : 0.f;
      }
      float* o = gates + (size_t)(s * 4 + g) * 3;
      o[0] = p0; o[1] = p1; o[2] = p2;
    }
  } else if (b < 1536) {
    const int idx = b - 1024;
    const int tr = (idx & 31) * 32, tc = ((idx >> 5) & 7) * 32;
    const int z = idx >> 8;
    const int off = z ? 1792 : 1280;
    unsigned short* dst = z ? vwinT : vselT;
    const int r = t >> 5, c = t & 31;
#pragma unroll
    for (int i = 0; i < 4; ++i)
      tile[r + i * 8][c] = C[(size_t)(tr + r + i * 8) * CSTR + off + tc + c];
    __syncthreads();
#pragma unroll
    for (int i = 0; i < 4; ++i)
      dst[(size_t)(tc + r + i * 8) * 1024 + tr + c] = f2bf(tile[c][r + i * 8]);
  } else {
    const int c = b - 1536;          // 0..63 (63 = zero pad)
    const int g = t >> 6, d = t & 63;
#pragma unroll
    for (int qq = 0; qq < 4; ++qq) {
      const int idx = t * 4 + qq;
      const int j = idx >> 5, dd = idx & 31;
      const float inv = powf(10000.f, -(float)dd * (1.f / 32.f));
      float sn, cs;
      sincosf((float)(c * 16 + j) * inv, &sn, &cs);
      csP[j][dd] = cs; snP[j][dd] = sn;
    }
    __syncthreads();
    float ak = 0.f, av = 0.f;
    if (c < SCMP) {
      const int d2 = d & 31;
      for (int j = 0; j < 32; ++j) {
        const int pos = c * 16 + j;
        const float k1 = C[(size_t)pos * CSTR + 2048 + g * 64 + d2];
        const float k2 = C[(size_t)pos * CSTR + 2048 + g * 64 + d2 + 32];
        ak += (d < 32) ? (k1 * csP[j][d2] - k2 * snP[j][d2])
                       : (k1 * snP[j][d2] + k2 * csP[j][d2]);
        av += C[(size_t)pos * CSTR + 2304 + g * 64 + d];
      }
      ak *= (1.f / 32.f); av *= (1.f / 32.f);
    }
    KcB[(size_t)(g * 64 + c) * 64 + d] = f2bf(ak);
    VcTB[(size_t)(g * 64 + d) * 64 + c] = f2bf(av);
  }
}

// ---------------- MFMA NSA attention (round-6 structure, LJF block order) ----------------
// grid = (64 qtiles of 16 rows, 4 groups, 2): z=0 -> cmp+sel (Ocs), z=1 -> win (Owin).
// qt = 63 - blockIdx.x: longest blocks (late qtiles) dispatch first -> shorter tail.
// 4 waves = 4 heads. Fixed-offset softmax, deferred denominator.
// Tile loop: 3-buffer LDS, 1-ahead prefetch, counted vmcnt(4), one raw s_barrier/tile.
__device__ __forceinline__ void stage_tile(
    const unsigned short* kbase, int krow,
    const unsigned short* vbase, int vrow,
    unsigned short* Kb, unsigned short* Vb, int tid)
{
#pragma unroll
  for (int i = 0; i < 2; ++i) {
    const int t2 = tid + i * 256;
    const int sf = t2 >> 7, sks = (t2 >> 6) & 1, skh = (t2 >> 4) & 3, stk = t2 & 15;
    gload_lds16(kbase + (size_t)(16 * sf + stk) * krow + sks * 32 + skh * 8, Kb + t2 * 8);
    gload_lds16(vbase + (size_t)(16 * sf + stk) * vrow + sks * 32 + skh * 8, Vb + t2 * 8);
  }
}

// BR: 0=cmp, 1=sel (per-row 16-bit block mask), 2=win (sliding window)
template<int BR>
__device__ __forceinline__ void attn_compute(
    int b, int s0, int l,
    bf16x8 aq0, bf16x8 aq1,
    float (&ps)[4], f32x4 (&Oa)[4],
    const unsigned short* Klds, const unsigned short* Vlds,
    float (*Pw)[68], const unsigned* selmaskS)
{
  const int kg = l >> 4, lr = l & 15;
  f32x4 sc[4];
  __builtin_amdgcn_s_setprio(1);
#pragma unroll
  for (int f = 0; f < 4; ++f) {
    sc[f] = (f32x4){0.f, 0.f, 0.f, 0.f};
    sc[f] = __builtin_amdgcn_mfma_f32_16x16x32_bf16(
        aq0, *(const bf16x8*)(Klds + (f * 2 + 0) * 512 + l * 8), sc[f], 0, 0, 0);
    sc[f] = __builtin_amdgcn_mfma_f32_16x16x32_bf16(
        aq1, *(const bf16x8*)(Klds + (f * 2 + 1) * 512 + l * 8), sc[f], 0, 0, 0);
  }
  __builtin_amdgcn_s_setprio(0);

#pragma unroll
  for (int r = 0; r < 4; ++r) {
    const int lrow = kg * 4 + r;
    const int sr = s0 + lrow;
#pragma unroll
    for (int f = 0; f < 4; ++f) {
      const int tok = b * 64 + 16 * f + lr;
      bool ok;
      if (BR == 0)      ok = (tok < SCMP) && (tok * 16 + 31 <= sr);
      else if (BR == 1) ok = ((selmaskS[lrow] >> b) & 1u) && (tok <= sr);
      else              ok = (tok <= sr) && (tok > sr - WWIN);
      const float p = ok ? __expf(sc[f][r] * SCALEF - EXPOFF) : 0.f;
      Pw[lrow][16 * f + lr] = p;
      ps[r] += p;
    }
  }
  asm volatile("s_waitcnt lgkmcnt(0)" ::: "memory");  // wave's P writes visible
#pragma unroll
  for (int ks = 0; ks < 2; ++ks) {
    const float4 pa0 = *(const float4*)&Pw[lr][ks * 32 + kg * 8];
    const float4 pa1 = *(const float4*)&Pw[lr][ks * 32 + kg * 8 + 4];
    const bf16x8 pa = pack8(pa0, pa1);
    __builtin_amdgcn_s_setprio(1);
#pragma unroll
    for (int f = 0; f < 4; ++f)
      Oa[f] = __builtin_amdgcn_mfma_f32_16x16x32_bf16(
          pa, *(const bf16x8*)(Vlds + (f * 2 + ks) * 512 + l * 8), Oa[f], 0, 0, 0);
    __builtin_amdgcn_s_setprio(0);
  }
}

#define TILE_SYNC(more) do { \
    __builtin_amdgcn_sched_barrier(0); \
    if (more) asm volatile("s_waitcnt vmcnt(4)" ::: "memory"); \
    else      asm volatile("s_waitcnt vmcnt(0)" ::: "memory"); \
    __builtin_amdgcn_sched_barrier(0); \
    __builtin_amdgcn_s_barrier(); \
    __builtin_amdgcn_sched_barrier(0); \
  } while (0)

__global__ __launch_bounds__(256) void attn_mfma_kernel(
    const unsigned short* __restrict__ qb,     // [S][16][64] bf16 (roped)
    const unsigned short* __restrict__ kselb,  // [S][256] bf16 (roped)
    const unsigned short* __restrict__ vselT,  // [256][S] bf16
    const unsigned short* __restrict__ kwinb,
    const unsigned short* __restrict__ vwinT,
    const unsigned short* __restrict__ KcB,    // [g*64+c][64] bf16
    const unsigned short* __restrict__ VcTB,   // [g*64+d][64] bf16
    const float* __restrict__ gates,           // [S][4][3]
    float* __restrict__ Ocs, float* __restrict__ Owin)
{
  const int qt = (int)gridDim.x - 1 - (int)blockIdx.x;   // longest-job-first
  const int g  = blockIdx.y;
  const int z  = blockIdx.z;
  const int s0 = qt * QBLK;
  const int tid = threadIdx.x;
  const int w = tid >> 6, l = tid & 63;    // w = head
  const int kg = l >> 4, lr = l & 15;
  const int bmax = s0 >> 6;

  __shared__ unsigned short Klds[3][4096];
  __shared__ unsigned short Vlds[3][4096];
  __shared__ float Plds[4][16][68];
  __shared__ float lgS[QBLK][16];
  __shared__ float lcS[4][16];
  __shared__ unsigned selmaskS[QBLK];
  __shared__ int selListS[16];
  __shared__ int nselS;

  if (tid < QBLK) selmaskS[tid] = 0u;

  const int sq = s0 + lr;
  const unsigned short* qrow = qb + (size_t)(sq * 16 + g * 4 + w) * 64;
  const bf16x8 aq0 = *(const bf16x8*)(qrow + kg * 8);
  const bf16x8 aq1 = *(const bf16x8*)(qrow + 32 + kg * 8);

  float gv[3][4];
#pragma unroll
  for (int r = 0; r < 4; ++r) {
    const int sr = s0 + kg * 4 + r;
    const float* gp = gates + (size_t)(sr * 4 + g) * 3;
    gv[0][r] = gp[0]; gv[1][r] = gp[1]; gv[2][r] = gp[2];
  }

  f32x4 Ot[4];
#pragma unroll
  for (int f = 0; f < 4; ++f) Ot[f] = (f32x4){0.f, 0.f, 0.f, 0.f};

  float ps[4], ls[4];
  f32x4 Oa[4];

#define ARESET() do { \
    _Pragma("unroll") for (int r = 0; r < 4; ++r) ps[r] = 0.f; \
    _Pragma("unroll") for (int f = 0; f < 4; ++f) Oa[f] = (f32x4){0.f,0.f,0.f,0.f}; \
  } while (0)
#define REDUCE_LS() do { \
    _Pragma("unroll") for (int r = 0; r < 4; ++r) { \
      ls[r] = ps[r]; \
      ls[r] += __shfl_xor(ls[r], 1); ls[r] += __shfl_xor(ls[r], 2); \
      ls[r] += __shfl_xor(ls[r], 4); ls[r] += __shfl_xor(ls[r], 8); } \
  } while (0)
#define AFINAL(bi) do { \
    _Pragma("unroll") for (int f = 0; f < 4; ++f) \
    _Pragma("unroll") for (int r = 0; r < 4; ++r) \
      Ot[f][r] += gv[bi][r] * ((ls[r] > 0.f) ? (Oa[f][r] / ls[r]) : 0.f); \
  } while (0)

  if (z == 0) {
    // ---- cmp branch (single tile) ----
    ARESET();
    stage_tile(KcB + (size_t)g * 64 * 64, 64, VcTB + (size_t)g * 64 * 64, 64,
               Klds[0], Vlds[0], tid);
    TILE_SYNC(0);
    attn_compute<0>(0, s0, l, aq0, aq1, ps, Oa, Klds[0], Vlds[0], Plds[w], selmaskS);
    REDUCE_LS();
    if ((l & 15) == 0) {
#pragma unroll
      for (int r = 0; r < 4; ++r) lcS[w][kg * 4 + r] = ls[r];
    }
    AFINAL(0);
    __syncthreads();   // cmp P + lcS visible block-wide

    // ---- selection: p_slc (M_MAP inline), lg, top-8 ----
    {
      const int row = tid >> 4, mm = tid & 15;
      float psl = 0.f;
#pragma unroll
      for (int hh = 0; hh < 4; ++hh) {
        const float lc = lcS[hh][row];
        if (lc > 0.f) {
          const int cb = 4 * mm;
          float a = Plds[hh][row][cb] + Plds[hh][row][cb + 1] + Plds[hh][row][cb + 2];
          if (cb >= 1)       a += 0.5f * Plds[hh][row][cb - 1];
          if (cb + 3 < SCMP) a += 0.5f * Plds[hh][row][cb + 3];
          psl += a / lc;
        }
      }
      const bool causal = (mm <= bmax);
      const bool forced = (mm == 0) || (mm == bmax);
      lgS[row][mm] = causal ? (psl + (forced ? 1e6f : 0.f)) : -1e9f;
    }
    __syncthreads();
    {
      const int row = tid >> 4, mm = tid & 15;
      const float my = lgS[row][mm];
      int rank = 0;
#pragma unroll
      for (int m2 = 0; m2 < 16; ++m2) {
        const float v = lgS[row][m2];
        if (v > my || (v == my && m2 < mm)) ++rank;
      }
      if (rank < NSELK && mm <= bmax) atomicOr(&selmaskS[row], 1u << mm);
    }
    __syncthreads();
    if (tid == 0) {
      unsigned u = 0;
      for (int r = 0; r < QBLK; ++r) u |= selmaskS[r];
      int n = 0;
      for (int b = 0; b < 16; ++b) if ((u >> b) & 1u) selListS[n++] = b;
      nselS = n;
    }
    __syncthreads();
    const int nt = nselS;   // >= 1

    // ---- sel branch: 3-buffer counted-vmcnt pipeline ----
    ARESET();
    {
      const int b0 = selListS[0];
      stage_tile(kselb + (size_t)b0 * 64 * 256 + g * 64, 256,
                 vselT + (size_t)g * 64 * 1024 + b0 * 64, 1024,
                 Klds[0], Vlds[0], tid);
      for (int i = 0; i < nt; ++i) {
        if (i + 1 < nt) {
          const int bn = selListS[i + 1];
          const int nb = (i + 1) % 3;
          stage_tile(kselb + (size_t)bn * 64 * 256 + g * 64, 256,
                     vselT + (size_t)g * 64 * 1024 + bn * 64, 1024,
                     Klds[nb], Vlds[nb], tid);
        }
        TILE_SYNC(i + 1 < nt);
        attn_compute<1>(selListS[i], s0, l, aq0, aq1, ps, Oa,
                        Klds[i % 3], Vlds[i % 3], Plds[w], selmaskS);
        __builtin_amdgcn_sched_barrier(0);
      }
    }
    REDUCE_LS();
    AFINAL(1);

#pragma unroll
    for (int f = 0; f < 4; ++f)
#pragma unroll
      for (int r = 0; r < 4; ++r) {
        const int sr = s0 + kg * 4 + r;
        Ocs[(size_t)(sr * 16 + g * 4 + w) * 64 + 16 * f + lr] = Ot[f][r];
      }
  } else {
    // ---- win branch: 3-buffer counted-vmcnt pipeline ----
    ARESET();
    const int blo = (s0 >= (WWIN - 1)) ? ((s0 - (WWIN - 1)) >> 6) : 0;
    const int nt = bmax - blo + 1;
    stage_tile(kwinb + (size_t)blo * 64 * 256 + g * 64, 256,
               vwinT + (size_t)g * 64 * 1024 + blo * 64, 1024,
               Klds[0], Vlds[0], tid);
    for (int i = 0; i < nt; ++i) {
      if (i + 1 < nt) {
        const int bn = blo + i + 1;
        const int nb = (i + 1) % 3;
        stage_tile(kwinb + (size_t)bn * 64 * 256 + g * 64, 256,
                   vwinT + (size_t)g * 64 * 1024 + bn * 64, 1024,
                   Klds[nb], Vlds[nb], tid);
      }
      TILE_SYNC(i + 1 < nt);
      attn_compute<2>(blo + i, s0, l, aq0, aq1, ps, Oa,
                      Klds[i % 3], Vlds[i % 3], Plds[w], selmaskS);
      __builtin_amdgcn_sched_barrier(0);
    }
    REDUCE_LS();
    AFINAL(2);

#pragma unroll
    for (int f = 0; f < 4; ++f)
#pragma unroll
      for (int r = 0; r < 4; ++r) {
        const int sr = s0 + kg * 4 + r;
        Owin[(size_t)(sr * 16 + g * 4 + w) * 64 + 16 * f + lr] = Ot[f][r];
      }
  }
#undef ARESET
#undef REDUCE_LS
#undef AFINAL
}

// ---------------- launch ----------------
extern "C" void kernel_launch(void* const* d_in, const int* in_sizes, int n_in,
                              void* d_out, int out_size, void* d_ws, size_t ws_size,
                              hipStream_t stream) {
  const float* x      = (const float*)d_in[0];
  const float* wq     = (const float*)d_in[1];
  const float* wk_sel = (const float*)d_in[2];
  const float* wv_sel = (const float*)d_in[3];
  const float* wk_win = (const float*)d_in[4];
  const float* wv_win = (const float*)d_in[5];
  const float* wk_cmp = (const float*)d_in[6];
  const float* wv_cmp = (const float*)d_in[7];
  const float* w_out  = (const float*)d_in[8];
  const float* g1w    = (const float*)d_in[9];
  const float* g1b    = (const float*)d_in[10];
  const float* g2w    = (const float*)d_in[11];
  const float* g2b    = (const float*)d_in[12];

  float* ws = (float*)d_ws;
  float* Cq    = ws;                          // 2,621,440
  float* gts   = Cq + 2621440;                // 12,288
  float* Ocs   = gts + 12288;                 // 1,048,576
  float* Owin  = Ocs + 1048576;               // 1,048,576

  unsigned short* xb     = (unsigned short*)(Owin + 1048576);  // 1,048,576
  unsigned short* wqkvb  = xb + 1048576;      // 2,621,440 (wq | 6 kv weights)
  unsigned short* w_outb = wqkvb + 2621440;   // 1,048,576
  unsigned short* q_b    = w_outb + 1048576;  // 1,048,576
  unsigned short* kselb  = q_b + 1048576;     // 262,144
  unsigned short* kwinb  = kselb + 262144;    // 262,144
  unsigned short* vselT  = kwinb + 262144;    // 262,144
  unsigned short* vwinT  = vselT + 262144;    // 262,144
  unsigned short* KcB    = vwinT + 262144;    // 16,384
  unsigned short* VcTB   = KcB + 16384;       // 16,384

  // inputs -> bf16 (weights contiguous: wq rows 0-1023, then 6 kv weights)
  ConvJobs j1 = {};
  j1.cnt = 9;
  j1.src[0] = x;      j1.dst[0] = (unsigned*)xb;                        j1.n4[0] = 262144;
  j1.src[1] = wq;     j1.dst[1] = (unsigned*)wqkvb;                     j1.n4[1] = 262144;
  j1.src[2] = wk_sel; j1.dst[2] = (unsigned*)(wqkvb + 1048576);         j1.n4[2] = 65536;
  j1.src[3] = wv_sel; j1.dst[3] = (unsigned*)(wqkvb + 1048576+262144);  j1.n4[3] = 65536;
  j1.src[4] = wk_win; j1.dst[4] = (unsigned*)(wqkvb + 1048576+524288);  j1.n4[4] = 65536;
  j1.src[5] = wv_win; j1.dst[5] = (unsigned*)(wqkvb + 1048576+786432);  j1.n4[5] = 65536;
  j1.src[6] = wk_cmp; j1.dst[6] = (unsigned*)(wqkvb + 1048576+1048576); j1.n4[6] = 65536;
  j1.src[7] = wv_cmp; j1.dst[7] = (unsigned*)(wqkvb + 1048576+1310720); j1.n4[7] = 65536;
  j1.src[8] = w_out;  j1.dst[8] = (unsigned*)w_outb;                    j1.n4[8] = 262144;
  conv_f32_bf16<<<1024, 256, 0, stream>>>(j1);

  // fused QKV projection: Cq[1024][2560] = x @ [wq; kv weights]^T  (64x64 tiles, 640 blocks)
  gemm_bf16<<<dim3(40, 16), 256, 0, stream>>>(xb, wqkvb, Cq, CSTR, 1024);

  // merged prep | transpose | pool
  mid_kernel<<<1600, 256, 0, stream>>>(Cq, g1w, g1b, g2w, g2b,
                                       q_b, kselb, kwinb, gts,
                                       vselT, vwinT, KcB, VcTB);

  // fused MFMA NSA attention (z=0: cmp+sel, z=1: win)
  attn_mfma_kernel<<<dim3(64, 4, 2), 256, 0, stream>>>(
      q_b, kselb, vselT, kwinb, vwinT, KcB, VcTB, gts, Ocs, Owin);

  // combine + output projection
  conv_add_bf16<<<1024, 256, 0, stream>>>(Ocs, Owin, (uint2*)xb);
  gemm_bf16<<<dim3(16, 16), 256, 0, stream>>>(xb, w_outb, (float*)d_out, 1024, 1024);
}